// Round 1
// baseline (329.617 us; speedup 1.0000x reference)
//
#include <hip/hip_runtime.h>

// Fully-fused CNN: conv1(3x3)+pool(3x3,s2)+relu -> conv2(3x3)+pool(3x3,s2)+relu -> conv3(4x4)
// One block per image (B=2048), 256 threads. All intermediates live in LDS.
// LDS budget: h1[64][12][12] (36KB) + regB 6400 floats (25.6KB, union of {input image, conv2
// staging, stage-3 partials}) = 62.5KB -> 2 blocks/CU (125KB of 160KB LDS).

__global__ __launch_bounds__(256) void convnet_fused(
    const float* __restrict__ x,   // [B,1,28,28]
    const float* __restrict__ w1,  // [64,1,3,3]
    const float* __restrict__ b1,  // [64]
    const float* __restrict__ w2,  // [64,64,3,3]
    const float* __restrict__ b2,  // [64]
    const float* __restrict__ w3,  // [10,64,4,4]
    const float* __restrict__ b3,  // [10]
    float* __restrict__ out)       // [B,10]
{
    __shared__ float lds[15616];
    float* h1   = lds;           // [64][12][12] = 9216 floats; later reused for h2[64][4][4]
    float* regB = lds + 9216;    // 6400 floats: img (784) -> conv2buf [64][100] -> partials

    const int n = blockIdx.x;
    const int t = threadIdx.x;
    const int c = t >> 2;        // 0..63 output channel
    const int q = t & 3;         // quadrant

    // ---- load input image into LDS ----
    const float* img_g = x + (size_t)n * 784;
    for (int i = t; i < 784; i += 256) regB[i] = img_g[i];
    __syncthreads();

    // ---- stage 1: conv1 3x3 + maxpool 3x3 s2 + relu -> h1[c][12][12] ----
    {
        const int oy = (q >> 1) * 6;   // pooled-quadrant origin
        const int ox = (q & 1) * 6;
        float w[9];
        #pragma unroll
        for (int k = 0; k < 9; ++k) w[k] = w1[c * 9 + k];
        const float bias = b1[c];

        for (int py = 0; py < 6; ++py) {
            for (int px = 0; px < 6; ++px) {
                const int ppy = oy + py, ppx = ox + px;      // pooled coords in [0,12)
                const int iy = 2 * ppy, ix = 2 * ppx;        // top-left of 5x5 input patch
                float p[25];
                #pragma unroll
                for (int r = 0; r < 5; ++r)
                    #pragma unroll
                    for (int s = 0; s < 5; ++s)
                        p[r * 5 + s] = regB[(iy + r) * 28 + ix + s];
                float m = -1e30f;
                #pragma unroll
                for (int a = 0; a < 3; ++a)
                    #pragma unroll
                    for (int b = 0; b < 3; ++b) {
                        float acc = bias;
                        #pragma unroll
                        for (int i = 0; i < 3; ++i)
                            #pragma unroll
                            for (int j = 0; j < 3; ++j)
                                acc += p[(a + i) * 5 + (b + j)] * w[i * 3 + j];
                        m = fmaxf(m, acc);
                    }
                h1[c * 144 + ppy * 12 + ppx] = fmaxf(m, 0.0f);
            }
        }
    }
    __syncthreads();

    // ---- stage 2a: conv2 3x3 (64 cin) -> conv2buf[c][10][10] in regB ----
    {
        const int oy = (q >> 1) * 5;   // 5x5 output quadrant origin
        const int ox = (q & 1) * 5;
        float acc[25];
        const float bias = b2[c];
        #pragma unroll
        for (int k = 0; k < 25; ++k) acc[k] = bias;

        const float* w2c = w2 + c * 576;
        for (int cin = 0; cin < 64; ++cin) {
            float w[9];
            #pragma unroll
            for (int k = 0; k < 9; ++k) w[k] = w2c[cin * 9 + k];
            float p[49];                         // 7x7 input patch for 5x5 outputs
            const float* h1c = h1 + cin * 144;
            #pragma unroll
            for (int r = 0; r < 7; ++r)
                #pragma unroll
                for (int s = 0; s < 7; ++s)
                    p[r * 7 + s] = h1c[(oy + r) * 12 + ox + s];
            #pragma unroll
            for (int yy = 0; yy < 5; ++yy)
                #pragma unroll
                for (int xx = 0; xx < 5; ++xx) {
                    float a = acc[yy * 5 + xx];
                    #pragma unroll
                    for (int i = 0; i < 3; ++i)
                        #pragma unroll
                        for (int j = 0; j < 3; ++j)
                            a += p[(yy + i) * 7 + (xx + j)] * w[i * 3 + j];
                    acc[yy * 5 + xx] = a;
                }
        }
        __syncthreads();   // img in regB is dead for everyone; safe to overwrite
        #pragma unroll
        for (int yy = 0; yy < 5; ++yy)
            #pragma unroll
            for (int xx = 0; xx < 5; ++xx)
                regB[c * 100 + (oy + yy) * 10 + (ox + xx)] = acc[yy * 5 + xx];
    }
    __syncthreads();

    // ---- stage 2b: maxpool 3x3 s2 + relu -> h2[c][4][4] in lds[0..1024) ----
    {
        const float* cb = regB + c * 100;
        float h2v[4];
        #pragma unroll
        for (int k = 0; k < 4; ++k) {
            const int pos = q * 4 + k;
            const int py = pos >> 2, px = pos & 3;
            float m = -1e30f;
            #pragma unroll
            for (int a = 0; a < 3; ++a)
                #pragma unroll
                for (int b = 0; b < 3; ++b)
                    m = fmaxf(m, cb[(2 * py + a) * 10 + (2 * px + b)]);
            h2v[k] = fmaxf(m, 0.0f);
        }
        __syncthreads();   // h1 region dead; conv2buf reads done
        #pragma unroll
        for (int k = 0; k < 4; ++k) {
            const int pos = q * 4 + k;
            lds[c * 16 + pos] = h2v[k];
        }
    }
    __syncthreads();

    // ---- stage 3: conv3 4x4 over 64 cin -> out[n][10] ----
    if (t < 160) {
        const int o = t >> 4;    // 0..9
        const int l = t & 15;    // 0..15
        const float* w3o = w3 + o * 1024;
        float s = 0.0f;
        #pragma unroll
        for (int cc = 0; cc < 4; ++cc) {
            const int cin = l * 4 + cc;
            #pragma unroll
            for (int k = 0; k < 16; ++k)
                s += lds[cin * 16 + k] * w3o[cin * 16 + k];
        }
        regB[t] = s;   // partials; conv2buf reads are done (synced above)
    }
    __syncthreads();
    if (t < 10) {
        float s = b3[t];
        #pragma unroll
        for (int l = 0; l < 16; ++l) s += regB[t * 16 + l];
        out[(size_t)n * 10 + t] = s;
    }
}

extern "C" void kernel_launch(void* const* d_in, const int* in_sizes, int n_in,
                              void* d_out, int out_size, void* d_ws, size_t ws_size,
                              hipStream_t stream) {
    const float* x  = (const float*)d_in[0];
    const float* w1 = (const float*)d_in[1];
    const float* b1 = (const float*)d_in[2];
    const float* w2 = (const float*)d_in[3];
    const float* b2 = (const float*)d_in[4];
    const float* w3 = (const float*)d_in[5];
    const float* b3 = (const float*)d_in[6];
    float* out = (float*)d_out;

    const int B = in_sizes[0] / 784;   // 2048
    convnet_fused<<<B, 256, 0, stream>>>(x, w1, b1, w2, b2, w3, b3, out);
}

// Round 2
// 149.962 us; speedup vs baseline: 2.1980x; 2.1980x over previous
//
#include <hip/hip_runtime.h>

// Fused CNN, conv2 via bf16 MFMA (16x16x32).
// conv1(3x3)+pool+relu (fp32 VALU) -> conv2(3x3) as implicit GEMM M=64,N=100(pad 112),K=576
// with K ordered (ky,kx,cin) -> pool+relu -> conv3(4x4) fp32.
// One block per image, 256 threads (4 waves; wave w owns couts [16w,16w+16)).
// LDS 46.3 KB -> 3 blocks/CU.

typedef __attribute__((ext_vector_type(8))) short short8;   // 8 x bf16 (4 VGPRs)
typedef __attribute__((ext_vector_type(4))) float f32x4;

__device__ inline short f2bf(float f) {   // fp32 -> bf16, round-to-nearest-even
    union { float f; unsigned u; } v; v.f = f;
    unsigned r = (v.u + 0x7FFFu + ((v.u >> 16) & 1u)) >> 16;
    return (short)r;
}

// w2r[s][cout][cin] (bf16), s = ky*3+kx: makes MFMA A-fragments contiguous in cin.
__global__ __launch_bounds__(256) void prep_w2(const float* __restrict__ w2,
                                               short* __restrict__ w2r) {
    int i = blockIdx.x * 256 + threadIdx.x;      // over 9*64*64 = 36864
    if (i >= 36864) return;
    int s = i >> 12, cout = (i >> 6) & 63, cin = i & 63;
    w2r[i] = f2bf(w2[cout * 576 + cin * 9 + s]);
}

__global__ __launch_bounds__(256) void convnet_fused(
    const float* __restrict__ x,   // [B,1,28,28]
    const float* __restrict__ w1,  // [64,1,3,3]
    const float* __restrict__ b1,  // [64]
    const short* __restrict__ w2r, // [9][64][64] bf16 (prep)
    const float* __restrict__ b2,  // [64]
    const float* __restrict__ w3,  // [10,64,4,4]
    const float* __restrict__ b3,  // [10]
    float* __restrict__ out)       // [B,10]
{
    // Region A: h1t[pos=144][cin stride 72] bf16 = 10368 shorts (5184 floats);
    //           reused as h2t[16 pos][64 cin] fp32 after conv2.
    // Region B: union(img 784f, conv2buf 64x100f, stage-3 partials 160f) = 6400 floats.
    __shared__ float lds_f[5184 + 6400];
    short* h1t = (short*)lds_f;
    float* h2t = lds_f;
    float* regB = lds_f + 5184;

    const int n_img = blockIdx.x;
    const int t = threadIdx.x;
    const int c = t >> 2;        // 0..63
    const int q = t & 3;         // quadrant

    // ---- load input image ----
    const float* img_g = x + (size_t)n_img * 784;
    for (int i = t; i < 784; i += 256) regB[i] = img_g[i];
    __syncthreads();

    // ---- stage 1: conv1 + pool 3x3 s2 + relu -> h1t[pos][c] (bf16) ----
    {
        const int oy = (q >> 1) * 6, ox = (q & 1) * 6;
        float w[9];
        #pragma unroll
        for (int k = 0; k < 9; ++k) w[k] = w1[c * 9 + k];
        const float bias = b1[c];

        for (int py = 0; py < 6; ++py) {
            #pragma unroll
            for (int px = 0; px < 6; ++px) {          // unrolled: LDS-load CSE across px
                const int ppy = oy + py, ppx = ox + px;
                const int iy = 2 * ppy, ix = 2 * ppx;
                float p[25];
                #pragma unroll
                for (int r = 0; r < 5; ++r)
                    #pragma unroll
                    for (int s = 0; s < 5; ++s)
                        p[r * 5 + s] = regB[(iy + r) * 28 + ix + s];
                float m = -1e30f;
                #pragma unroll
                for (int a = 0; a < 3; ++a)
                    #pragma unroll
                    for (int b = 0; b < 3; ++b) {
                        float acc = bias;
                        #pragma unroll
                        for (int i = 0; i < 3; ++i)
                            #pragma unroll
                            for (int j = 0; j < 3; ++j)
                                acc += p[(a + i) * 5 + (b + j)] * w[i * 3 + j];
                        m = fmaxf(m, acc);
                    }
                h1t[(ppy * 12 + ppx) * 72 + c] = f2bf(fmaxf(m, 0.0f));
            }
        }
    }
    __syncthreads();

    // ---- stage 2: conv2 as MFMA GEMM ----
    const int wv = t >> 6, lane = t & 63;
    const int quad = lane >> 4, mrow = lane & 15;
    {
        int base_el[7];
        #pragma unroll
        for (int nt = 0; nt < 7; ++nt) {
            int n = nt * 16 + mrow; if (n > 99) n = 99;   // clamp pad cols (discarded)
            int y = n / 10, xx = n - y * 10;
            base_el[nt] = (y * 12 + xx) * 72;
        }
        f32x4 acc[7];
        #pragma unroll
        for (int nt = 0; nt < 7; ++nt) acc[nt] = (f32x4){0.f, 0.f, 0.f, 0.f};

        #pragma unroll
        for (int ks = 0; ks < 18; ++ks) {
            const int s = ks >> 1, h = ks & 1;
            const int ky = s / 3, kx = s - ky * 3;
            const short8 a = *(const short8*)(w2r + s * 4096 + (wv * 16 + mrow) * 64
                                              + h * 32 + quad * 8);
            #pragma unroll
            for (int nt = 0; nt < 7; ++nt) {
                const short8 b = *(const short8*)(h1t + base_el[nt]
                                                  + (ky * 12 + kx) * 72 + h * 32 + quad * 8);
                acc[nt] = __builtin_amdgcn_mfma_f32_16x16x32_bf16(a, b, acc[nt], 0, 0, 0);
            }
        }
        __syncthreads();   // all h1t reads + img reads done; regB reusable
        // epilogue: D[row=quad*4+r][col=mrow] -> conv2buf[cout][pos] + bias
        #pragma unroll
        for (int nt = 0; nt < 7; ++nt) {
            const int n = nt * 16 + mrow;
            if (n < 100) {
                #pragma unroll
                for (int r = 0; r < 4; ++r) {
                    const int cout = wv * 16 + quad * 4 + r;
                    regB[cout * 100 + n] = acc[nt][r] + b2[cout];
                }
            }
        }
    }
    __syncthreads();

    // ---- stage 2b: pool 3x3 s2 + relu -> h2t[pos][cin] fp32 (region A, h1t dead) ----
    {
        const float* cb = regB + c * 100;
        #pragma unroll
        for (int k = 0; k < 4; ++k) {
            const int pos = q * 4 + k;
            const int py = pos >> 2, px = pos & 3;
            float m = -1e30f;
            #pragma unroll
            for (int a = 0; a < 3; ++a)
                #pragma unroll
                for (int b = 0; b < 3; ++b)
                    m = fmaxf(m, cb[(2 * py + a) * 10 + (2 * px + b)]);
            h2t[pos * 64 + c] = fmaxf(m, 0.0f);
        }
    }
    __syncthreads();

    // ---- stage 3: conv3 4x4 -> out[n][10]; h2t layout keeps reads 2-way (free) ----
    if (t < 160) {
        const int o = t >> 4, l = t & 15;
        const float* w3o = w3 + o * 1024;
        float s = 0.0f;
        #pragma unroll
        for (int cc = 0; cc < 4; ++cc) {
            const int cin = l * 4 + cc;
            #pragma unroll
            for (int k = 0; k < 16; ++k)
                s += h2t[k * 64 + cin] * w3o[cin * 16 + k];
        }
        regB[t] = s;
    }
    __syncthreads();
    if (t < 10) {
        float s = b3[t];
        #pragma unroll
        for (int l = 0; l < 16; ++l) s += regB[t * 16 + l];
        out[(size_t)n_img * 10 + t] = s;
    }
}

extern "C" void kernel_launch(void* const* d_in, const int* in_sizes, int n_in,
                              void* d_out, int out_size, void* d_ws, size_t ws_size,
                              hipStream_t stream) {
    const float* x  = (const float*)d_in[0];
    const float* w1 = (const float*)d_in[1];
    const float* b1 = (const float*)d_in[2];
    const float* w2 = (const float*)d_in[3];
    const float* b2 = (const float*)d_in[4];
    const float* w3 = (const float*)d_in[5];
    const float* b3 = (const float*)d_in[6];
    float* out = (float*)d_out;
    short* w2r = (short*)d_ws;            // 36864 bf16 = 73728 B

    const int B = in_sizes[0] / 784;      // 2048
    prep_w2<<<144, 256, 0, stream>>>(w2, w2r);
    convnet_fused<<<B, 256, 0, stream>>>(x, w1, b1, w2r, b2, w3, b3, out);
}

// Round 3
// 111.976 us; speedup vs baseline: 2.9437x; 1.3392x over previous
//
#include <hip/hip_runtime.h>

// Fused CNN, conv2 via bf16 MFMA (16x16x32).
// R3: (a) LDS 46.6->29.7 KB by overlaying conv2buf on dead h1t+img -> 5 blocks/CU;
//     (b) stage-1 computes each conv value once (ring-buffered rows + colmax),
//         1521 FMA + 225 LDS reads per thread vs 2916/450 with 9x window recompute.

typedef __attribute__((ext_vector_type(8))) short short8;   // 8 x bf16 (4 VGPRs)
typedef __attribute__((ext_vector_type(4))) float f32x4;

__device__ inline short f2bf(float f) {   // fp32 -> bf16, round-to-nearest-even
    union { float f; unsigned u; } v; v.f = f;
    unsigned r = (v.u + 0x7FFFu + ((v.u >> 16) & 1u)) >> 16;
    return (short)r;
}

// w2r[s][cout][cin] (bf16), s = ky*3+kx: MFMA A-fragments contiguous in cin.
__global__ __launch_bounds__(256) void prep_w2(const float* __restrict__ w2,
                                               short* __restrict__ w2r) {
    int i = blockIdx.x * 256 + threadIdx.x;      // 9*64*64 = 36864
    if (i >= 36864) return;
    int s = i >> 12, cout = (i >> 6) & 63, cin = i & 63;
    w2r[i] = f2bf(w2[cout * 576 + cin * 9 + s]);
}

__global__ __launch_bounds__(256) void convnet_fused(
    const float* __restrict__ x,   // [B,1,28,28]
    const float* __restrict__ w1,  // [64,1,3,3]
    const float* __restrict__ b1,  // [64]
    const short* __restrict__ w2r, // [9][64][64] bf16 (prep)
    const float* __restrict__ b2,  // [64]
    const float* __restrict__ w3,  // [10,64,4,4]
    const float* __restrict__ b3,  // [10]
    float* __restrict__ out)       // [B,10]
{
    // Overlay plan (floats):
    //   [0..5184)    h1t bf16 [144 pos][72 cin-stride]  -> later conv2buf fp32 [64][100] ([0..6400))
    //   [5184..5968) img 28x28                          -> (absorbed by conv2buf)
    //   [6400..7424) h2t fp32 [16 pos][64 cin]
    //   [0..160)     stage-3 partials (conv2buf dead by then)
    __shared__ float lds_f[7424];                // 29696 B -> 5 blocks/CU
    short* h1t  = (short*)lds_f;
    float* img  = lds_f + 5184;
    float* cbuf = lds_f;                         // conv2buf fp32 [64][100]
    float* h2t  = lds_f + 6400;
    float* prt  = lds_f;

    const int n_img = blockIdx.x;
    const int t = threadIdx.x;
    const int c = t >> 2;        // 0..63
    const int q = t & 3;         // quadrant

    // ---- load input image ----
    const float* img_g = x + (size_t)n_img * 784;
    for (int i = t; i < 784; i += 256) img[i] = img_g[i];
    __syncthreads();

    // ---- stage 1: conv1 + pool 3x3 s2 + relu -> h1t[pos][c] (bf16), no recompute ----
    {
        const int oy = (q >> 1) * 6, ox = (q & 1) * 6;   // pooled quadrant origin
        const int iy0 = 2 * oy, ix0 = 2 * ox;            // input/conv region origin
        float w[9];
        #pragma unroll
        for (int k = 0; k < 9; ++k) w[k] = w1[c * 9 + k];
        const float bias = b1[c];

        float in0[15], in1[15], in2[15];                 // ring of 3 input rows
        #pragma unroll
        for (int s = 0; s < 15; ++s) in0[s] = img[(iy0 + 0) * 28 + ix0 + s];
        #pragma unroll
        for (int s = 0; s < 15; ++s) in1[s] = img[(iy0 + 1) * 28 + ix0 + s];
        float cm[3][6];                                  // colmax ring (3 conv rows)

        #pragma unroll
        for (int r = 0; r < 13; ++r) {                   // conv rows, computed once
            #pragma unroll
            for (int s = 0; s < 15; ++s) in2[s] = img[(iy0 + r + 2) * 28 + ix0 + s];
            #pragma unroll
            for (int px = 0; px < 6; ++px) cm[r % 3][px] = -1e30f;
            #pragma unroll
            for (int xx = 0; xx < 13; ++xx) {
                float a = bias;
                #pragma unroll
                for (int j = 0; j < 3; ++j) {
                    a += in0[xx + j] * w[j];
                    a += in1[xx + j] * w[3 + j];
                    a += in2[xx + j] * w[6 + j];
                }
                // fold conv value into colmax: px with 2px <= xx <= 2px+2
                if ((xx & 1) == 0) {
                    if (xx >= 2 && xx <= 12) cm[r % 3][xx / 2 - 1] = fmaxf(cm[r % 3][xx / 2 - 1], a);
                    if (xx <= 10)            cm[r % 3][xx / 2]     = fmaxf(cm[r % 3][xx / 2], a);
                } else {
                    cm[r % 3][xx / 2] = fmaxf(cm[r % 3][xx / 2], a);
                }
            }
            if (r >= 2 && (r & 1) == 0) {                // pooled row py = r/2 - 1 complete
                const int py = r / 2 - 1;
                #pragma unroll
                for (int px = 0; px < 6; ++px) {
                    float m = fmaxf(fmaxf(cm[0][px], cm[1][px]), cm[2][px]);
                    h1t[((oy + py) * 12 + ox + px) * 72 + c] = f2bf(fmaxf(m, 0.0f));
                }
            }
            #pragma unroll
            for (int s = 0; s < 15; ++s) { in0[s] = in1[s]; in1[s] = in2[s]; }
        }
    }
    __syncthreads();

    // ---- stage 2: conv2 as MFMA GEMM (M=64 cout, N=100 pad 112, K=576) ----
    const int wv = t >> 6, lane = t & 63;
    const int quad = lane >> 4, mrow = lane & 15;
    {
        int base_el[7];
        #pragma unroll
        for (int nt = 0; nt < 7; ++nt) {
            int n = nt * 16 + mrow; if (n > 99) n = 99;   // clamp pad cols (discarded)
            int y = n / 10, xx = n - y * 10;
            base_el[nt] = (y * 12 + xx) * 72;
        }
        f32x4 acc[7];
        #pragma unroll
        for (int nt = 0; nt < 7; ++nt) acc[nt] = (f32x4){0.f, 0.f, 0.f, 0.f};

        #pragma unroll
        for (int ks = 0; ks < 18; ++ks) {
            const int s = ks >> 1, h = ks & 1;
            const int ky = s / 3, kx = s - ky * 3;
            const short8 a = *(const short8*)(w2r + s * 4096 + (wv * 16 + mrow) * 64
                                              + h * 32 + quad * 8);
            #pragma unroll
            for (int nt = 0; nt < 7; ++nt) {
                const short8 b = *(const short8*)(h1t + base_el[nt]
                                                  + (ky * 12 + kx) * 72 + h * 32 + quad * 8);
                acc[nt] = __builtin_amdgcn_mfma_f32_16x16x32_bf16(a, b, acc[nt], 0, 0, 0);
            }
        }
        __syncthreads();   // all h1t + img reads done; overlay region reusable
        // epilogue: D[row=quad*4+r][col=mrow] -> cbuf[cout][pos] + bias
        #pragma unroll
        for (int nt = 0; nt < 7; ++nt) {
            const int n = nt * 16 + mrow;
            if (n < 100) {
                #pragma unroll
                for (int r = 0; r < 4; ++r) {
                    const int cout = wv * 16 + quad * 4 + r;
                    cbuf[cout * 100 + n] = acc[nt][r] + b2[cout];
                }
            }
        }
    }
    __syncthreads();

    // ---- stage 2b: pool 3x3 s2 + relu -> h2t[pos][cin] fp32 ----
    {
        const float* cb = cbuf + c * 100;
        #pragma unroll
        for (int k = 0; k < 4; ++k) {
            const int pos = q * 4 + k;
            const int py = pos >> 2, px = pos & 3;
            float m = -1e30f;
            #pragma unroll
            for (int a = 0; a < 3; ++a)
                #pragma unroll
                for (int b = 0; b < 3; ++b)
                    m = fmaxf(m, cb[(2 * py + a) * 10 + (2 * px + b)]);
            h2t[pos * 64 + c] = fmaxf(m, 0.0f);
        }
    }
    __syncthreads();

    // ---- stage 3: conv3 4x4 -> out[n][10] ----
    if (t < 160) {
        const int o = t >> 4, l = t & 15;
        const float* w3o = w3 + o * 1024;
        float s = 0.0f;
        #pragma unroll
        for (int cc = 0; cc < 4; ++cc) {
            const int cin = l * 4 + cc;
            const float4 wv4a = *(const float4*)(w3o + cin * 16);
            const float4 wv4b = *(const float4*)(w3o + cin * 16 + 4);
            const float4 wv4c = *(const float4*)(w3o + cin * 16 + 8);
            const float4 wv4d = *(const float4*)(w3o + cin * 16 + 12);
            const float* hh = h2t + cin;           // h2t[k*64+cin], 2-way banks
            s += hh[0*64] * wv4a.x + hh[1*64] * wv4a.y + hh[2*64] * wv4a.z + hh[3*64] * wv4a.w;
            s += hh[4*64] * wv4b.x + hh[5*64] * wv4b.y + hh[6*64] * wv4b.z + hh[7*64] * wv4b.w;
            s += hh[8*64] * wv4c.x + hh[9*64] * wv4c.y + hh[10*64] * wv4c.z + hh[11*64] * wv4c.w;
            s += hh[12*64] * wv4d.x + hh[13*64] * wv4d.y + hh[14*64] * wv4d.z + hh[15*64] * wv4d.w;
        }
        prt[t] = s;   // cbuf dead (pool reads barriered above)
    }
    __syncthreads();
    if (t < 10) {
        float s = b3[t];
        #pragma unroll
        for (int l = 0; l < 16; ++l) s += prt[t * 16 + l];
        out[(size_t)n_img * 10 + t] = s;
    }
}

extern "C" void kernel_launch(void* const* d_in, const int* in_sizes, int n_in,
                              void* d_out, int out_size, void* d_ws, size_t ws_size,
                              hipStream_t stream) {
    const float* x  = (const float*)d_in[0];
    const float* w1 = (const float*)d_in[1];
    const float* b1 = (const float*)d_in[2];
    const float* w2 = (const float*)d_in[3];
    const float* b2 = (const float*)d_in[4];
    const float* w3 = (const float*)d_in[5];
    const float* b3 = (const float*)d_in[6];
    float* out = (float*)d_out;
    short* w2r = (short*)d_ws;            // 36864 bf16 = 73728 B

    const int B = in_sizes[0] / 784;      // 2048
    prep_w2<<<144, 256, 0, stream>>>(w2, w2r);
    convnet_fused<<<B, 256, 0, stream>>>(x, w1, b1, w2r, b2, w3, b3, out);
}